// Round 1
// baseline (505.663 us; speedup 1.0000x reference)
//
#include <hip/hip_runtime.h>
#include <cstdint>
#include <cstddef>

#define FP8_MAX 448.0f
#define KDIM 2048
#define NDIM 2048

typedef _Float16 half8 __attribute__((ext_vector_type(8)));
typedef float floatx4 __attribute__((ext_vector_type(4)));

__device__ __forceinline__ float fabs4max(float4 v) {
  return fmaxf(fmaxf(fabsf(v.x), fabsf(v.y)), fmaxf(fabsf(v.z), fabsf(v.w)));
}

__device__ __forceinline__ _Float16 quant1(float v, float inv) {
  return (_Float16)rintf(fminf(fmaxf(v * inv, -FP8_MAX), FP8_MAX));
}

__device__ __forceinline__ void gload_lds16(const void* g, void* l) {
  __builtin_amdgcn_global_load_lds(
      (const __attribute__((address_space(1))) unsigned int*)g,
      (__attribute__((address_space(3))) unsigned int*)l,
      16, 0, 0);
}

// ---------------- kernel 1: global |x| max ----------------
__global__ __launch_bounds__(256) void k_amax(const float4* __restrict__ x4, int n4,
                                              float* __restrict__ amax) {
  float m = 0.f;
  int stride = gridDim.x * blockDim.x;
  for (int i = blockIdx.x * blockDim.x + threadIdx.x; i < n4; i += stride)
    m = fmaxf(m, fabs4max(x4[i]));
#pragma unroll
  for (int off = 32; off > 0; off >>= 1)
    m = fmaxf(m, __shfl_xor(m, off));
  if ((threadIdx.x & 63) == 0)
    atomicMax((int*)amax, __float_as_int(m));  // all values >= 0: int-order == float-order
}

// ---------------- kernel 2: quantize x -> fp16 ----------------
__global__ __launch_bounds__(256) void k_xquant(const float4* __restrict__ x4,
                                                const float* __restrict__ amax,
                                                half8* __restrict__ xq, int n8) {
  float scale = fmaxf(amax[0] / FP8_MAX, 1e-12f);
  float inv = 1.f / scale;
  int stride = gridDim.x * blockDim.x;
  for (int i = blockIdx.x * blockDim.x + threadIdx.x; i < n8; i += stride) {
    float4 a = x4[2 * i];
    float4 b = x4[2 * i + 1];
    half8 q;
    q[0] = quant1(a.x, inv); q[1] = quant1(a.y, inv);
    q[2] = quant1(a.z, inv); q[3] = quant1(a.w, inv);
    q[4] = quant1(b.x, inv); q[5] = quant1(b.y, inv);
    q[6] = quant1(b.z, inv); q[7] = quant1(b.w, inv);
    xq[i] = q;
  }
}

// ---------------- kernel 3: per-row weight quant + combined scale ----------------
__global__ __launch_bounds__(256) void k_wquant(const float* __restrict__ w,
                                                const float* __restrict__ amax,
                                                _Float16* __restrict__ wq,
                                                float* __restrict__ comb) {
  int row = blockIdx.x;
  int t = threadIdx.x;
  const float4* w4 = (const float4*)(w + (size_t)row * KDIM);
  float4 a = w4[2 * t];
  float4 b = w4[2 * t + 1];
  float m = fmaxf(fabs4max(a), fabs4max(b));
#pragma unroll
  for (int off = 32; off > 0; off >>= 1)
    m = fmaxf(m, __shfl_xor(m, off));
  __shared__ float red[4];
  if ((t & 63) == 0) red[t >> 6] = m;
  __syncthreads();
  float rowmax = fmaxf(fmaxf(red[0], red[1]), fmaxf(red[2], red[3]));
  float wscale = fmaxf(rowmax / FP8_MAX, 1e-12f);
  float inv = 1.f / wscale;
  half8 q;
  q[0] = quant1(a.x, inv); q[1] = quant1(a.y, inv);
  q[2] = quant1(a.z, inv); q[3] = quant1(a.w, inv);
  q[4] = quant1(b.x, inv); q[5] = quant1(b.y, inv);
  q[6] = quant1(b.z, inv); q[7] = quant1(b.w, inv);
  *(half8*)(wq + (size_t)row * KDIM + t * 8) = q;
  if (t == 0) {
    float iscale = fmaxf(amax[0] / FP8_MAX, 1e-12f);
    comb[row] = iscale * wscale;
  }
}

// ---------------- kernel 4: fp16 GEMM (m97 structure) + dequant epilogue ----------------
// C[m][n] = (sum_k A[m][k]*B[n][k]) * comb[n] + bias[n]
__global__ __launch_bounds__(256) void k_gemm(const _Float16* __restrict__ A,
                                              const _Float16* __restrict__ B,
                                              const float* __restrict__ comb,
                                              const float* __restrict__ bias,
                                              float* __restrict__ C, int M) {
  __shared__ _Float16 As[128 * 32];
  __shared__ _Float16 Bs[128 * 32];

  int nwg = gridDim.x;
  int bid = blockIdx.x;
  int swz = bid;
  if ((nwg & 7) == 0) {
    int cpx = nwg >> 3;
    swz = (bid & 7) * cpx + (bid >> 3);
  }
  const int NB = NDIM / 128;  // 16
  int bm = swz / NB, bn = swz % NB;

  int tid = threadIdx.x;
  int lane = tid & 63;
  int wave = tid >> 6;
  int wr = wave >> 1, wc = wave & 1;

  const floatx4 zero4 = {0.f, 0.f, 0.f, 0.f};
  floatx4 acc[4][4];
#pragma unroll
  for (int i = 0; i < 4; ++i)
#pragma unroll
    for (int j = 0; j < 4; ++j) acc[i][j] = zero4;

  const _Float16* Ab = A + (size_t)bm * 128 * KDIM;
  const _Float16* Bb = B + (size_t)bn * 128 * KDIM;
  int trow = tid >> 2;          // staging: row within tile for this thread (j=0)
  int tcol = (tid & 3) * 8;     // staging: col within tile

  // LDS read bases: lane l holds frag row (lane&15), k = (lane>>4)*8..+8
  int ar = (wr * 64 + (lane & 15)) * 32 + (lane >> 4) * 8;
  int br = (wc * 64 + (lane & 15)) * 32 + (lane >> 4) * 8;

  for (int kt = 0; kt < KDIM / 32; ++kt) {
    if (kt) __syncthreads();
    const _Float16* ga = Ab + kt * 32;
    const _Float16* gb = Bb + kt * 32;
    gload_lds16(ga + (size_t)trow * KDIM + tcol, (char*)As + tid * 16);
    gload_lds16(ga + (size_t)(trow + 64) * KDIM + tcol, (char*)As + 4096 + tid * 16);
    gload_lds16(gb + (size_t)trow * KDIM + tcol, (char*)Bs + tid * 16);
    gload_lds16(gb + (size_t)(trow + 64) * KDIM + tcol, (char*)Bs + 4096 + tid * 16);
    __syncthreads();  // compiler drains vmcnt before barrier -> staged data visible

    half8 af[4], bf[4];
#pragma unroll
    for (int m = 0; m < 4; ++m) af[m] = *(const half8*)&As[ar + m * 16 * 32];
#pragma unroll
    for (int n = 0; n < 4; ++n) bf[n] = *(const half8*)&Bs[br + n * 16 * 32];
#pragma unroll
    for (int m = 0; m < 4; ++m)
#pragma unroll
      for (int n = 0; n < 4; ++n)
        acc[m][n] = __builtin_amdgcn_mfma_f32_16x16x32_f16(af[m], bf[n], acc[m][n], 0, 0, 0);
  }

  // epilogue: C/D layout col = lane&15, row = (lane>>4)*4 + j
  size_t row0 = (size_t)bm * 128 + wr * 64 + ((lane >> 4) << 2);
  int col0 = bn * 128 + wc * 64 + (lane & 15);
#pragma unroll
  for (int n = 0; n < 4; ++n) {
    int col = col0 + n * 16;
    float s = comb[col];
    float bb = bias[col];
#pragma unroll
    for (int m = 0; m < 4; ++m) {
      float* cp = C + (row0 + m * 16) * NDIM + col;
#pragma unroll
      for (int j = 0; j < 4; ++j)
        cp[(size_t)j * NDIM] = acc[m][n][j] * s + bb;
    }
  }
}

extern "C" void kernel_launch(void* const* d_in, const int* in_sizes, int n_in,
                              void* d_out, int out_size, void* d_ws, size_t ws_size,
                              hipStream_t stream) {
  const float* x = (const float*)d_in[0];
  const float* w = (const float*)d_in[1];
  const float* bias = (const float*)d_in[2];
  float* out = (float*)d_out;
  int M = in_sizes[0] / KDIM;  // 16384

  char* ws = (char*)d_ws;
  size_t xq_bytes = (size_t)in_sizes[0] * sizeof(_Float16);  // 64 MiB
  size_t wq_bytes = (size_t)in_sizes[1] * sizeof(_Float16);  // 8 MiB
  _Float16* xq = (_Float16*)ws;
  _Float16* wq = (_Float16*)(ws + xq_bytes);
  float* comb = (float*)(ws + xq_bytes + wq_bytes);
  float* amax = (float*)(ws + xq_bytes + wq_bytes + 8192);

  hipMemsetAsync(amax, 0, sizeof(float), stream);  // 0.0f bits; all |x| >= 0

  int n4 = in_sizes[0] / 4;
  k_amax<<<2048, 256, 0, stream>>>((const float4*)x, n4, amax);

  int n8 = in_sizes[0] / 8;
  k_xquant<<<2048, 256, 0, stream>>>((const float4*)x, amax, (half8*)xq, n8);

  k_wquant<<<NDIM, 256, 0, stream>>>(w, amax, wq, comb);

  int grid = (M / 128) * (NDIM / 128);  // 2048
  k_gemm<<<grid, 256, 0, stream>>>(xq, wq, comb, bias, out, M);
}

// Round 2
// 388.843 us; speedup vs baseline: 1.3004x; 1.3004x over previous
//
#include <hip/hip_runtime.h>
#include <cstdint>
#include <cstddef>

#define FP8_MAX 448.0f
#define KDIM 2048
#define NDIM 2048

typedef _Float16 half8 __attribute__((ext_vector_type(8)));
typedef float floatx4 __attribute__((ext_vector_type(4)));

__device__ __forceinline__ float fabs4max(float4 v) {
  return fmaxf(fmaxf(fabsf(v.x), fabsf(v.y)), fmaxf(fabsf(v.z), fabsf(v.w)));
}

__device__ __forceinline__ _Float16 quant1(float v, float inv) {
  return (_Float16)rintf(fminf(fmaxf(v * inv, -FP8_MAX), FP8_MAX));
}

__device__ __forceinline__ void gload_lds16(const void* g, void* l) {
  __builtin_amdgcn_global_load_lds(
      (const __attribute__((address_space(1))) unsigned int*)g,
      (__attribute__((address_space(3))) unsigned int*)l,
      16, 0, 0);
}

// ---------------- kernel 1a: per-block |x| max (no atomics) ----------------
__global__ __launch_bounds__(256) void k_amax(const float4* __restrict__ x4, int n4,
                                              float* __restrict__ partial) {
  float m = 0.f;
  int stride = gridDim.x * blockDim.x;
  for (int i = blockIdx.x * blockDim.x + threadIdx.x; i < n4; i += stride)
    m = fmaxf(m, fabs4max(x4[i]));
#pragma unroll
  for (int off = 32; off > 0; off >>= 1)
    m = fmaxf(m, __shfl_xor(m, off));
  __shared__ float red[4];
  if ((threadIdx.x & 63) == 0) red[threadIdx.x >> 6] = m;
  __syncthreads();
  if (threadIdx.x == 0)
    partial[blockIdx.x] = fmaxf(fmaxf(red[0], red[1]), fmaxf(red[2], red[3]));
}

// ---------------- kernel 1b: reduce partials -> amax ----------------
__global__ __launch_bounds__(256) void k_amax2(const float* __restrict__ partial, int n,
                                               float* __restrict__ amax) {
  int t = threadIdx.x;
  float m = 0.f;
  for (int i = t; i < n; i += 256) m = fmaxf(m, partial[i]);
#pragma unroll
  for (int off = 32; off > 0; off >>= 1)
    m = fmaxf(m, __shfl_xor(m, off));
  __shared__ float red[4];
  if ((t & 63) == 0) red[t >> 6] = m;
  __syncthreads();
  if (t == 0) amax[0] = fmaxf(fmaxf(red[0], red[1]), fmaxf(red[2], red[3]));
}

// ---------------- kernel 2: quantize x -> fp16 ----------------
__global__ __launch_bounds__(256) void k_xquant(const float4* __restrict__ x4,
                                                const float* __restrict__ amax,
                                                half8* __restrict__ xq, int n8) {
  float scale = fmaxf(amax[0] / FP8_MAX, 1e-12f);
  float inv = 1.f / scale;
  int stride = gridDim.x * blockDim.x;
  for (int i = blockIdx.x * blockDim.x + threadIdx.x; i < n8; i += stride) {
    float4 a = x4[2 * i];
    float4 b = x4[2 * i + 1];
    half8 q;
    q[0] = quant1(a.x, inv); q[1] = quant1(a.y, inv);
    q[2] = quant1(a.z, inv); q[3] = quant1(a.w, inv);
    q[4] = quant1(b.x, inv); q[5] = quant1(b.y, inv);
    q[6] = quant1(b.z, inv); q[7] = quant1(b.w, inv);
    xq[i] = q;
  }
}

// ---------------- kernel 3: per-row weight quant + combined scale ----------------
__global__ __launch_bounds__(256) void k_wquant(const float* __restrict__ w,
                                                const float* __restrict__ amax,
                                                _Float16* __restrict__ wq,
                                                float* __restrict__ comb) {
  int row = blockIdx.x;
  int t = threadIdx.x;
  const float4* w4 = (const float4*)(w + (size_t)row * KDIM);
  float4 a = w4[2 * t];
  float4 b = w4[2 * t + 1];
  float m = fmaxf(fabs4max(a), fabs4max(b));
#pragma unroll
  for (int off = 32; off > 0; off >>= 1)
    m = fmaxf(m, __shfl_xor(m, off));
  __shared__ float red[4];
  if ((t & 63) == 0) red[t >> 6] = m;
  __syncthreads();
  float rowmax = fmaxf(fmaxf(red[0], red[1]), fmaxf(red[2], red[3]));
  float wscale = fmaxf(rowmax / FP8_MAX, 1e-12f);
  float inv = 1.f / wscale;
  half8 q;
  q[0] = quant1(a.x, inv); q[1] = quant1(a.y, inv);
  q[2] = quant1(a.z, inv); q[3] = quant1(a.w, inv);
  q[4] = quant1(b.x, inv); q[5] = quant1(b.y, inv);
  q[6] = quant1(b.z, inv); q[7] = quant1(b.w, inv);
  *(half8*)(wq + (size_t)row * KDIM + t * 8) = q;
  if (t == 0) {
    float iscale = fmaxf(amax[0] / FP8_MAX, 1e-12f);
    comb[row] = iscale * wscale;
  }
}

// ---------------- kernel 4: 256x256 tile fp16 GEMM, BK=32, 3-buffer counted-vmcnt ----------------
// C[m][n] = (sum_k A[m][k]*B[n][k]) * comb[n] + bias[n]
// 512 threads = 8 waves (2M x 4N), per-wave 128x64 output, acc[8][4] f32x4.
// LDS: 3 buffers x (A 16KB + B 16KB) = 96KB. Stage runs 2 K-tiles ahead ->
// boundary wait is vmcnt(4), never a full drain. Raw s_barrier (2/tile).
// LDS chunk-swizzle: linear gload_lds dest + pre-swizzled global source +
// swizzled ds_read (chunk ^= row bits[2:1]) to break the 8-way bank conflict.
__global__ __launch_bounds__(512, 2) void k_gemm256(const _Float16* __restrict__ A,
                                                    const _Float16* __restrict__ B,
                                                    const float* __restrict__ comb,
                                                    const float* __restrict__ bias,
                                                    float* __restrict__ C, int M) {
  __shared__ _Float16 smem[3 * 16384];  // 96 KiB

  const int NT = KDIM / 32;  // 64 K-tiles
  int nwg = gridDim.x;
  int bid = blockIdx.x;
  int swz = bid;
  if ((nwg & 7) == 0) {
    int cpx = nwg >> 3;
    swz = (bid & 7) * cpx + (bid >> 3);
  }
  const int NBN = NDIM / 256;  // 8
  int bm = swz / NBN, bn = swz % NBN;

  int tid = threadIdx.x;
  int lane = tid & 63;
  int w = tid >> 6;
  int wr = w >> 2;   // 0..1
  int wc = w & 3;    // 0..3

  // ---- staging constants (pre-swizzled global source, linear LDS dest) ----
  int sR = tid >> 2;                         // row 0..127 (first half)
  int sc = (tid & 3) ^ ((tid >> 3) & 3);     // chunk ^ rowbits[2:1]
  const _Float16* gA = A + (size_t)bm * 256 * KDIM;
  const _Float16* gB = B + (size_t)bn * 256 * KDIM;
  size_t off0 = (size_t)sR * KDIM + sc * 8;
  size_t off1 = (size_t)(sR + 128) * KDIM + sc * 8;

  // ---- ds_read fragment offsets (swizzled) ----
  int g = lane >> 4;
  int lr = lane & 15;
  int gx = g ^ ((lr >> 1) & 3);
  int aOff = (wr * 128 + lr) * 64 + gx * 16;  // bytes within A region
  int bOff = (wc * 64 + lr) * 64 + gx * 16;   // bytes within B region

  const floatx4 zero4 = {0.f, 0.f, 0.f, 0.f};
  floatx4 acc[8][4];
#pragma unroll
  for (int i = 0; i < 8; ++i)
#pragma unroll
    for (int j = 0; j < 4; ++j) acc[i][j] = zero4;

#define STAGE_A(t, buf)                                                        \
  do {                                                                         \
    const _Float16* src = gA + (size_t)(t)*32;                                 \
    char* dst = (char*)smem + (buf)*32768;                                     \
    gload_lds16(src + off0, dst + tid * 16);                                   \
    gload_lds16(src + off1, dst + 8192 + tid * 16);                            \
  } while (0)
#define STAGE_B(t, buf)                                                        \
  do {                                                                         \
    const _Float16* src = gB + (size_t)(t)*32;                                 \
    char* dst = (char*)smem + (buf)*32768 + 16384;                             \
    gload_lds16(src + off0, dst + tid * 16);                                   \
    gload_lds16(src + off1, dst + 8192 + tid * 16);                            \
  } while (0)

  // ---- prologue: stage tiles 0 and 1, wait for tile 0 only ----
  STAGE_A(0, 0); STAGE_B(0, 0);
  STAGE_A(1, 1); STAGE_B(1, 1);
  asm volatile("s_waitcnt vmcnt(4)" ::: "memory");
  __builtin_amdgcn_s_barrier();

  half8 af[4], bf[4];
  for (int t = 0; t < NT; ++t) {
    int buf = t % 3;
    const char* Abuf = (const char*)smem + buf * 32768;
    const char* Bbuf = Abuf + 16384;
    int nbuf = (t + 2) % 3;
    bool do_stage = (t + 2 < NT);

    // ---- phase 0 (mh = 0) ----
#pragma unroll
    for (int n = 0; n < 4; ++n) bf[n] = *(const half8*)(Bbuf + bOff + n * 1024);
#pragma unroll
    for (int m = 0; m < 4; ++m) af[m] = *(const half8*)(Abuf + aOff + m * 1024);
    if (do_stage) STAGE_A(t + 2, nbuf);
    __builtin_amdgcn_s_setprio(1);
#pragma unroll
    for (int m = 0; m < 4; ++m)
#pragma unroll
      for (int n = 0; n < 4; ++n)
        acc[m][n] = __builtin_amdgcn_mfma_f32_16x16x32_f16(af[m], bf[n], acc[m][n], 0, 0, 0);
    __builtin_amdgcn_s_setprio(0);
    __builtin_amdgcn_s_barrier();

    // ---- phase 1 (mh = 1) ----
#pragma unroll
    for (int m = 0; m < 4; ++m) af[m] = *(const half8*)(Abuf + aOff + 4096 + m * 1024);
    if (do_stage) STAGE_B(t + 2, nbuf);
    __builtin_amdgcn_s_setprio(1);
#pragma unroll
    for (int m = 0; m < 4; ++m)
#pragma unroll
      for (int n = 0; n < 4; ++n)
        acc[4 + m][n] = __builtin_amdgcn_mfma_f32_16x16x32_f16(af[m], bf[n], acc[4 + m][n], 0, 0, 0);
    __builtin_amdgcn_s_setprio(0);

    // ---- tile boundary: reads drained, counted vmcnt, barrier ----
    asm volatile("s_waitcnt lgkmcnt(0)" ::: "memory");
    if (t < NT - 2)
      asm volatile("s_waitcnt vmcnt(4)" ::: "memory");
    else
      asm volatile("s_waitcnt vmcnt(0)" ::: "memory");
    __builtin_amdgcn_s_barrier();
  }
#undef STAGE_A
#undef STAGE_B

  // ---- epilogue: dequant + bias, C/D layout col=lane&15, row=(lane>>4)*4+j ----
  int cbase = bn * 256 + wc * 64 + (lane & 15);
  float s[4], bv[4];
#pragma unroll
  for (int n = 0; n < 4; ++n) {
    s[n] = comb[cbase + n * 16];
    bv[n] = bias[cbase + n * 16];
  }
#pragma unroll
  for (int mh = 0; mh < 2; ++mh)
#pragma unroll
    for (int m = 0; m < 4; ++m) {
      size_t row = (size_t)bm * 256 + wr * 128 + mh * 64 + m * 16 + ((lane >> 4) << 2);
      float* cp = C + row * NDIM + cbase;
#pragma unroll
      for (int n = 0; n < 4; ++n)
#pragma unroll
        for (int j = 0; j < 4; ++j)
          cp[n * 16 + (size_t)j * NDIM] = acc[mh * 4 + m][n][j] * s[n] + bv[n];
    }
}

extern "C" void kernel_launch(void* const* d_in, const int* in_sizes, int n_in,
                              void* d_out, int out_size, void* d_ws, size_t ws_size,
                              hipStream_t stream) {
  const float* x = (const float*)d_in[0];
  const float* w = (const float*)d_in[1];
  const float* bias = (const float*)d_in[2];
  float* out = (float*)d_out;
  int M = in_sizes[0] / KDIM;  // 16384

  char* ws = (char*)d_ws;
  size_t xq_bytes = (size_t)in_sizes[0] * sizeof(_Float16);  // 64 MiB
  size_t wq_bytes = (size_t)in_sizes[1] * sizeof(_Float16);  // 8 MiB
  _Float16* xq = (_Float16*)ws;
  _Float16* wq = (_Float16*)(ws + xq_bytes);
  float* comb = (float*)(ws + xq_bytes + wq_bytes);
  float* amax = (float*)(ws + xq_bytes + wq_bytes + 8192);
  float* partial = (float*)(ws + xq_bytes + wq_bytes + 8192 + 256);

  const int AMAX_BLOCKS = 2048;
  int n4 = in_sizes[0] / 4;
  k_amax<<<AMAX_BLOCKS, 256, 0, stream>>>((const float4*)x, n4, partial);
  k_amax2<<<1, 256, 0, stream>>>(partial, AMAX_BLOCKS, amax);

  int n8 = in_sizes[0] / 8;
  k_xquant<<<2048, 256, 0, stream>>>((const float4*)x, amax, (half8*)xq, n8);

  k_wquant<<<NDIM, 256, 0, stream>>>(w, amax, wq, comb);

  int grid = (M / 256) * (NDIM / 256);  // 512
  k_gemm256<<<grid, 512, 0, stream>>>(xq, wq, comb, bias, out, M);
}